// Round 1
// baseline (418443.506 us; speedup 1.0000x reference)
//
#include <hip/hip_runtime.h>
#include <stdint.h>

#define HID 1024
#define NLAYERS 8
#define NLET 100
#define T_TOTAL 4096
#define S_TOTAL (T_TOTAL * NLAYERS) /* 32768 sequential cell steps */

// ---------- helpers ----------
__device__ __forceinline__ uint32_t f2bf(float f) {
    // round-to-nearest-even fp32 -> bf16 (inputs are small uniforms; no NaN/Inf care needed)
    uint32_t u = __float_as_uint(f);
    return (u + 0x7FFFu + ((u >> 16) & 1u)) >> 16;
}
__device__ __forceinline__ float bflo(uint32_t p) { return __uint_as_float(p << 16); }
__device__ __forceinline__ float bfhi(uint32_t p) { return __uint_as_float(p & 0xFFFF0000u); }
__device__ __forceinline__ float sigm(float x) { return 1.0f / (1.0f + __expf(-x)); }
__device__ __forceinline__ float tanh_f(float x) {
    float xx = fminf(fmaxf(x, -15.0f), 15.0f);
    float e = __expf(2.0f * xx);
    return (e - 1.0f) / (e + 1.0f);
}

// ---------- kernel 0: init the tagged h-slot buffers (ws is poisoned 0xAA each call) ----------
__global__ void init_slots(uint64_t* hslots) {
    int i = threadIdx.x;                       // 1024 threads
    hslots[i] = 0ULL;                          // parity 0: seq=0, h=0.0f  (initial state)
    hslots[HID + i] = 0xFFFFFFFF00000000ULL;   // parity 1: seq that never matches
}

// ---------- kernel 1: persistent stacked-LSTM scan ----------
// 256 blocks x 1024 threads, 1 block/CU, all resident. Block b owns units {4b..4b+3}.
// wave = (u, j): unit u = wave&3, layer-slot j = wave>>2 handles layers j and j+4.
// Lane L owns h-columns [16L,16L+16) and x-columns {2L,2L+1} (L<50).
__global__ void __launch_bounds__(1024, 4)
lstm_persistent(const float* __restrict__ website, const float* __restrict__ payload,
                const float* __restrict__ W_ih, const float* __restrict__ W_hh,
                const float* __restrict__ b_ih, const float* __restrict__ b_hh,
                uint64_t* hslots, float* c_out) {
    __shared__ float h_lds[2][HID];  // double-buffered by step parity
    __shared__ float c_lds[4];

    const int tid = threadIdx.x;
    const int b = blockIdx.x;       // 0..255
    const int wave = tid >> 6;      // 0..15
    const int lane = tid & 63;
    const int u = wave & 3;         // unit within block
    const int j = wave >> 2;        // 0..3 : handles layers j and j+4
    const int k = b * 4 + u;        // global hidden unit 0..1023

    // ---- one-time: load this wave's weights into registers as packed bf16 ----
    uint32_t wh[2][4][8];  // [layer-slot ls][gate row r][8 packed pairs of 16 h-cols]
    uint32_t wx[2][4];     // packed pair of 2 x-cols (zero for lanes >= 50)
    float bias[2][4];
#pragma unroll
    for (int ls = 0; ls < 2; ++ls) {
        const int l = j + 4 * ls;
#pragma unroll
        for (int r = 0; r < 4; ++r) {
            const int row = k + 1024 * r;  // gate rows: i, f, g, o
            const float* src = W_hh + ((size_t)(l * 4096 + row)) * 1024 + lane * 16;
#pragma unroll
            for (int c = 0; c < 8; ++c) {
                wh[ls][r][c] = f2bf(src[2 * c]) | (f2bf(src[2 * c + 1]) << 16);
            }
            if (lane < 50) {
                const float* sx = W_ih + ((size_t)(l * 4096 + row)) * NLET + lane * 2;
                wx[ls][r] = f2bf(sx[0]) | (f2bf(sx[1]) << 16);
            } else {
                wx[ls][r] = 0u;
            }
            bias[ls][r] = b_ih[l * 4096 + row] + b_hh[l * 4096 + row];
        }
    }
    if (tid < 4) c_lds[tid] = 0.0f;
    __syncthreads();

    // ---- the 32768-step scan; layer loop fully unrolled so ls/parity are compile-time ----
#define STEP_BODY(LCONST)                                                                     \
    do {                                                                                      \
        constexpr int lc = (LCONST);                                                          \
        constexpr int lsX = lc >> 2;                                                          \
        constexpr int pin = lc & 1;        /* parity of sm1 = t*8+lc */                       \
        constexpr int pout = (lc + 1) & 1; /* parity of s */                                  \
        const int sm1 = t * 8 + lc;                                                           \
        const int s = sm1 + 1;                                                                \
        const bool active = ((lc & 3) == j);                                                  \
        float x0 = 0.f, x1 = 0.f;                                                             \
        if (active && lane < 50) {                                                            \
            const float* xp = (t < 2048) ? (website + (size_t)t * NLET)                       \
                                         : (payload + (size_t)(t - 2048) * NLET);             \
            x0 = xp[lane * 2];                                                                \
            x1 = xp[lane * 2 + 1];                                                            \
        }                                                                                     \
        {                                                                                     \
            uint64_t* slot = hslots + (size_t)pin * HID + tid;                                \
            uint64_t v = __hip_atomic_load(slot, __ATOMIC_RELAXED, __HIP_MEMORY_SCOPE_AGENT); \
            while ((uint32_t)(v >> 32) != (uint32_t)sm1) {                                    \
                __builtin_amdgcn_s_sleep(1);                                                  \
                v = __hip_atomic_load(slot, __ATOMIC_RELAXED, __HIP_MEMORY_SCOPE_AGENT);      \
            }                                                                                 \
            h_lds[pin][tid] = __uint_as_float((uint32_t)v);                                   \
        }                                                                                     \
        __syncthreads();                                                                      \
        if (active) {                                                                         \
            const float4* hp = (const float4*)(&h_lds[pin][lane * 16]);                       \
            float4 q0 = hp[0], q1 = hp[1], q2 = hp[2], q3 = hp[3];                            \
            float hv[16] = {q0.x, q0.y, q0.z, q0.w, q1.x, q1.y, q1.z, q1.w,                   \
                            q2.x, q2.y, q2.z, q2.w, q3.x, q3.y, q3.z, q3.w};                  \
            float acc0 = 0.f, acc1 = 0.f, acc2 = 0.f, acc3 = 0.f;                             \
            _Pragma("unroll") for (int c8 = 0; c8 < 8; ++c8) {                                \
                float hA = hv[2 * c8], hB = hv[2 * c8 + 1];                                   \
                uint32_t p0 = wh[lsX][0][c8];                                                 \
                acc0 = fmaf(bflo(p0), hA, acc0); acc0 = fmaf(bfhi(p0), hB, acc0);             \
                uint32_t p1 = wh[lsX][1][c8];                                                 \
                acc1 = fmaf(bflo(p1), hA, acc1); acc1 = fmaf(bfhi(p1), hB, acc1);             \
                uint32_t p2 = wh[lsX][2][c8];                                                 \
                acc2 = fmaf(bflo(p2), hA, acc2); acc2 = fmaf(bfhi(p2), hB, acc2);             \
                uint32_t p3 = wh[lsX][3][c8];                                                 \
                acc3 = fmaf(bflo(p3), hA, acc3); acc3 = fmaf(bfhi(p3), hB, acc3);             \
            }                                                                                 \
            {                                                                                 \
                uint32_t px;                                                                  \
                px = wx[lsX][0]; acc0 = fmaf(bflo(px), x0, acc0);                             \
                acc0 = fmaf(bfhi(px), x1, acc0);                                              \
                px = wx[lsX][1]; acc1 = fmaf(bflo(px), x0, acc1);                             \
                acc1 = fmaf(bfhi(px), x1, acc1);                                              \
                px = wx[lsX][2]; acc2 = fmaf(bflo(px), x0, acc2);                             \
                acc2 = fmaf(bfhi(px), x1, acc2);                                              \
                px = wx[lsX][3]; acc3 = fmaf(bflo(px), x0, acc3);                             \
                acc3 = fmaf(bfhi(px), x1, acc3);                                              \
            }                                                                                 \
            _Pragma("unroll") for (int mm = 32; mm > 0; mm >>= 1) {                           \
                acc0 += __shfl_xor(acc0, mm, 64);                                             \
                acc1 += __shfl_xor(acc1, mm, 64);                                             \
                acc2 += __shfl_xor(acc2, mm, 64);                                             \
                acc3 += __shfl_xor(acc3, mm, 64);                                             \
            }                                                                                 \
            float cprev = c_lds[u];                                                           \
            float gi = sigm(acc0 + bias[lsX][0]);                                             \
            float gf = sigm(acc1 + bias[lsX][1]);                                             \
            float gg = tanh_f(acc2 + bias[lsX][2]);                                           \
            float go = sigm(acc3 + bias[lsX][3]);                                             \
            float cn = fmaf(gf, cprev, gi * gg);                                              \
            float hn = go * tanh_f(cn);                                                       \
            if (lane == 0) {                                                                  \
                c_lds[u] = cn;                                                                \
                uint64_t nv =                                                                 \
                    ((uint64_t)(uint32_t)s << 32) | (uint64_t)__float_as_uint(hn);            \
                __hip_atomic_store(&hslots[(size_t)pout * HID + k], nv, __ATOMIC_RELAXED,     \
                                   __HIP_MEMORY_SCOPE_AGENT);                                 \
            }                                                                                 \
        }                                                                                     \
    } while (0)

    for (int t = 0; t < T_TOTAL; ++t) {
        STEP_BODY(0);
        STEP_BODY(1);
        STEP_BODY(2);
        STEP_BODY(3);
        STEP_BODY(4);
        STEP_BODY(5);
        STEP_BODY(6);
        STEP_BODY(7);
    }
#undef STEP_BODY

    __syncthreads();
    if (tid < 4) c_out[b * 4 + tid] = c_lds[tid];
}

// ---------- kernel 2: the head — feat = W_lin@c + b_lin; out = sigmoid(W_out@feat + b_out) ----------
__global__ void head_kernel(const float* __restrict__ c_out, const float* __restrict__ W_lin,
                            const float* __restrict__ b_lin, const float* __restrict__ W_out,
                            const float* __restrict__ b_out, float* out) {
    const int lane = threadIdx.x;  // 64 threads, one wave
    float cv[16];
    const float4* cp = (const float4*)(c_out + lane * 16);
#pragma unroll
    for (int q = 0; q < 4; ++q) {
        float4 v = cp[q];
        cv[4 * q + 0] = v.x;
        cv[4 * q + 1] = v.y;
        cv[4 * q + 2] = v.z;
        cv[4 * q + 3] = v.w;
    }
    float fsum = 0.f;
#pragma unroll
    for (int i = 0; i < 16; ++i) {
        const float* w = W_lin + (size_t)i * HID + lane * 16;
        float a = 0.f;
#pragma unroll
        for (int m = 0; m < 16; ++m) a = fmaf(w[m], cv[m], a);
#pragma unroll
        for (int mm = 32; mm > 0; mm >>= 1) a += __shfl_xor(a, mm, 64);
        fsum = fmaf(W_out[i], a + b_lin[i], fsum);
    }
    if (lane == 0) out[0] = sigm(fsum + b_out[0]);
}

extern "C" void kernel_launch(void* const* d_in, const int* in_sizes, int n_in, void* d_out,
                              int out_size, void* d_ws, size_t ws_size, hipStream_t stream) {
    (void)in_sizes; (void)n_in; (void)out_size; (void)ws_size;
    const float* website = (const float*)d_in[0];
    const float* payload = (const float*)d_in[1];
    const float* W_ih = (const float*)d_in[2];
    const float* W_hh = (const float*)d_in[3];
    const float* b_ih = (const float*)d_in[4];
    const float* b_hh = (const float*)d_in[5];
    const float* W_lin = (const float*)d_in[6];
    const float* b_lin = (const float*)d_in[7];
    const float* W_out = (const float*)d_in[8];
    const float* b_out = (const float*)d_in[9];

    uint64_t* hslots = (uint64_t*)d_ws;                      // 2 * 1024 * 8 B = 16 KB
    float* c_out = (float*)((char*)d_ws + 2 * HID * 8);      // 4 KB

    init_slots<<<1, 1024, 0, stream>>>(hslots);
    lstm_persistent<<<256, 1024, 0, stream>>>(website, payload, W_ih, W_hh, b_ih, b_hh, hslots,
                                              c_out);
    head_kernel<<<1, 64, 0, stream>>>(c_out, W_lin, b_lin, W_out, b_out, (float*)d_out);
}

// Round 2
// 295937.061 us; speedup vs baseline: 1.4140x; 1.4140x over previous
//
#include <hip/hip_runtime.h>
#include <stdint.h>

#define HID 1024
#define NLAYERS 8
#define NLET 100
#define T_TOTAL 4096

typedef uint32_t u32x4 __attribute__((ext_vector_type(4)));

// ---------- helpers ----------
__device__ __forceinline__ uint32_t f2bf(float f) {
    uint32_t u = __float_as_uint(f);
    return (u + 0x7FFFu + ((u >> 16) & 1u)) >> 16;
}
__device__ __forceinline__ float bflo(uint32_t p) { return __uint_as_float(p << 16); }
__device__ __forceinline__ float bfhi(uint32_t p) { return __uint_as_float(p & 0xFFFF0000u); }
__device__ __forceinline__ float sigm(float x) { return 1.0f / (1.0f + __expf(-x)); }
__device__ __forceinline__ float tanh_f(float x) {
    float xx = fminf(fmaxf(x, -15.0f), 15.0f);
    float e = __expf(2.0f * xx);
    return (e - 1.0f) / (e + 1.0f);
}

// device-coherent (bypass L1+L2) wide ops
__device__ __forceinline__ void store_coh_x4(void* p, u32x4 d) {
    asm volatile("global_store_dwordx4 %0, %1, off sc0 sc1" ::"v"(p), "v"(d) : "memory");
}
__device__ __forceinline__ void load_coh_2x4(const void* p0, const void* p1, u32x4& a, u32x4& b) {
    asm volatile(
        "global_load_dwordx4 %0, %2, off sc0 sc1\n\t"
        "global_load_dwordx4 %1, %3, off sc0 sc1\n\t"
        "s_waitcnt vmcnt(0)"
        : "=v"(a), "=v"(b)
        : "v"(p0), "v"(p1)
        : "memory");
}

// ---------- kernel 1: persistent stacked-LSTM scan ----------
// 256 blocks x 256 threads (4 waves), 1 block/CU. Block b owns units {4b..4b+3};
// wave u owns unit k=4b+u for ALL 8 layers (weights register-resident, bf16-packed).
// Lane L owns h-columns {2L+128p, 2L+128p+1 : p=0..7} and x-columns {2L,2L+1} (L<50).
// Broadcast: per-consumer-group mailbox replicas. Chunk = 4 x {fp32 h, u32 tag} = 32B.
// mail layout: [(copy*2 + parity)*256 + producer] * 32 bytes.
__global__ void __launch_bounds__(256, 1)
lstm_persistent(const float* __restrict__ website, const float* __restrict__ payload,
                const float* __restrict__ W_ih, const float* __restrict__ W_hh,
                const float* __restrict__ b_ih, const float* __restrict__ b_hh,
                char* mail, float* c_out, int ncopies) {
    __shared__ float h_lds[HID];
    __shared__ float h_new[4];

    const int tid = threadIdx.x;    // 0..255
    const int b = blockIdx.x;       // 0..255
    const int u = tid >> 6;         // wave 0..3 = unit within block
    const int lane = tid & 63;
    const int k = b * 4 + u;        // global hidden unit
    const int rcopy = b & (ncopies - 1);

    // ---- one-time: pack this wave's weights into registers as bf16 pairs ----
    uint32_t wh[NLAYERS][4][8];  // [layer][gate][pair p] -> cols (2L+128p, 2L+128p+1)
    uint32_t wx[NLAYERS][4];     // x-cols (2L, 2L+1), zero for lanes >= 50
    float bias[NLAYERS][4];
#pragma unroll
    for (int l = 0; l < NLAYERS; ++l) {
#pragma unroll
        for (int g = 0; g < 4; ++g) {
            const int row = 1024 * g + k;
            const float* src = W_hh + ((size_t)(l * 4096 + row)) * 1024;
#pragma unroll
            for (int p = 0; p < 8; ++p) {
                const int c0 = 2 * lane + 128 * p;
                wh[l][g][p] = f2bf(src[c0]) | (f2bf(src[c0 + 1]) << 16);
            }
            if (lane < 50) {
                const float* sx = W_ih + ((size_t)(l * 4096 + row)) * NLET + 2 * lane;
                wx[l][g] = f2bf(sx[0]) | (f2bf(sx[1]) << 16);
            } else {
                wx[l][g] = 0u;
            }
            bias[l][g] = b_ih[l * 4096 + row] + b_hh[l * 4096 + row];
        }
    }

    // init h(0)=0, c(0)=0
    ((float4*)h_lds)[tid] = make_float4(0.f, 0.f, 0.f, 0.f);
    float c = 0.0f;
    __syncthreads();

    for (int t = 0; t < T_TOTAL; ++t) {
        // x for this timestep (shared by all 8 layers)
        float x0 = 0.f, x1 = 0.f;
        if (lane < 50) {
            const float* xp = (t < 2048) ? (website + (size_t)t * NLET)
                                         : (payload + (size_t)(t - 2048) * NLET);
            x0 = xp[2 * lane];
            x1 = xp[2 * lane + 1];
        }
#pragma unroll
        for (int l = 0; l < NLAYERS; ++l) {
            const int s = t * NLAYERS + l + 1;  // step being produced (1..32768)
            const int par = s & 1;

            // ---- compute this wave's unit: 4 gate dot-products over h + x ----
            float2 hv[8];
#pragma unroll
            for (int p = 0; p < 8; ++p)
                hv[p] = *(const float2*)&h_lds[2 * lane + 128 * p];
            float acc0 = 0.f, acc1 = 0.f, acc2 = 0.f, acc3 = 0.f;
#pragma unroll
            for (int p = 0; p < 8; ++p) {
                const float hA = hv[p].x, hB = hv[p].y;
                uint32_t w;
                w = wh[l][0][p]; acc0 = fmaf(bflo(w), hA, acc0); acc0 = fmaf(bfhi(w), hB, acc0);
                w = wh[l][1][p]; acc1 = fmaf(bflo(w), hA, acc1); acc1 = fmaf(bfhi(w), hB, acc1);
                w = wh[l][2][p]; acc2 = fmaf(bflo(w), hA, acc2); acc2 = fmaf(bfhi(w), hB, acc2);
                w = wh[l][3][p]; acc3 = fmaf(bflo(w), hA, acc3); acc3 = fmaf(bfhi(w), hB, acc3);
            }
            {
                uint32_t w;
                w = wx[l][0]; acc0 = fmaf(bflo(w), x0, acc0); acc0 = fmaf(bfhi(w), x1, acc0);
                w = wx[l][1]; acc1 = fmaf(bflo(w), x0, acc1); acc1 = fmaf(bfhi(w), x1, acc1);
                w = wx[l][2]; acc2 = fmaf(bflo(w), x0, acc2); acc2 = fmaf(bfhi(w), x1, acc2);
                w = wx[l][3]; acc3 = fmaf(bflo(w), x0, acc3); acc3 = fmaf(bfhi(w), x1, acc3);
            }
#pragma unroll
            for (int mm = 32; mm > 0; mm >>= 1) {
                acc0 += __shfl_xor(acc0, mm, 64);
                acc1 += __shfl_xor(acc1, mm, 64);
                acc2 += __shfl_xor(acc2, mm, 64);
                acc3 += __shfl_xor(acc3, mm, 64);
            }
            const float gi = sigm(acc0 + bias[l][0]);
            const float gf = sigm(acc1 + bias[l][1]);
            const float gg = tanh_f(acc2 + bias[l][2]);
            const float go = sigm(acc3 + bias[l][3]);
            c = fmaf(gf, c, gi * gg);
            const float hn = go * tanh_f(c);
            if (lane == 0) h_new[u] = hn;
            __syncthreads();  // h_new ready; everyone done reading h_lds

            // ---- push: store this block's 32B chunk to every mailbox copy ----
            const float f0 = h_new[0], f1 = h_new[1], f2 = h_new[2], f3 = h_new[3];
            if (tid < ncopies) {
                char* dst = mail + ((size_t)((tid * 2 + par) * 256 + b)) * 32;
                u32x4 d0, d1;
                d0.x = __float_as_uint(f0); d0.y = (uint32_t)s;
                d0.z = __float_as_uint(f1); d0.w = (uint32_t)s;
                d1.x = __float_as_uint(f2); d1.y = (uint32_t)s;
                d1.z = __float_as_uint(f3); d1.w = (uint32_t)s;
                store_coh_x4(dst, d0);
                store_coh_x4(dst + 16, d1);
            }

            // ---- poll: thread t collects producer t's chunk from our copy ----
            {
                const char* srcp = mail + ((size_t)((rcopy * 2 + par) * 256 + tid)) * 32;
                u32x4 a0, a1;
                for (;;) {
                    load_coh_2x4(srcp, srcp + 16, a0, a1);
                    if (a0.y == (uint32_t)s && a0.w == (uint32_t)s &&
                        a1.y == (uint32_t)s && a1.w == (uint32_t)s)
                        break;
                    __builtin_amdgcn_s_sleep(2);
                }
                h_lds[4 * tid + 0] = __uint_as_float(a0.x);
                h_lds[4 * tid + 1] = __uint_as_float(a0.z);
                h_lds[4 * tid + 2] = __uint_as_float(a1.x);
                h_lds[4 * tid + 3] = __uint_as_float(a1.z);
            }
            __syncthreads();  // h_lds now holds h(s)
        }
    }

    if (lane == 0) c_out[k] = c;
}

// ---------- kernel 2: head — out = sigmoid(W_out @ (W_lin@c + b_lin) + b_out) ----------
__global__ void head_kernel(const float* __restrict__ c_out, const float* __restrict__ W_lin,
                            const float* __restrict__ b_lin, const float* __restrict__ W_out,
                            const float* __restrict__ b_out, float* out) {
    const int lane = threadIdx.x;  // 64 threads, one wave
    float cv[16];
    const float4* cp = (const float4*)(c_out + lane * 16);
#pragma unroll
    for (int q = 0; q < 4; ++q) {
        float4 v = cp[q];
        cv[4 * q + 0] = v.x;
        cv[4 * q + 1] = v.y;
        cv[4 * q + 2] = v.z;
        cv[4 * q + 3] = v.w;
    }
    float fsum = 0.f;
#pragma unroll
    for (int i = 0; i < 16; ++i) {
        const float* w = W_lin + (size_t)i * HID + lane * 16;
        float a = 0.f;
#pragma unroll
        for (int m = 0; m < 16; ++m) a = fmaf(w[m], cv[m], a);
#pragma unroll
        for (int mm = 32; mm > 0; mm >>= 1) a += __shfl_xor(a, mm, 64);
        fsum = fmaf(W_out[i], a + b_lin[i], fsum);
    }
    if (lane == 0) out[0] = sigm(fsum + b_out[0]);
}

extern "C" void kernel_launch(void* const* d_in, const int* in_sizes, int n_in, void* d_out,
                              int out_size, void* d_ws, size_t ws_size, hipStream_t stream) {
    (void)in_sizes; (void)n_in; (void)out_size;
    const float* website = (const float*)d_in[0];
    const float* payload = (const float*)d_in[1];
    const float* W_ih = (const float*)d_in[2];
    const float* W_hh = (const float*)d_in[3];
    const float* b_ih = (const float*)d_in[4];
    const float* b_hh = (const float*)d_in[5];
    const float* W_lin = (const float*)d_in[6];
    const float* b_lin = (const float*)d_in[7];
    const float* W_out = (const float*)d_in[8];
    const float* b_out = (const float*)d_in[9];

    // mailbox replicas: ncopies * 2(par) * 256(producers) * 32B = ncopies * 16 KiB
    int ncopies = 64;
    while (ncopies > 1 && (size_t)ncopies * 16384 + 4096 > ws_size) ncopies >>= 1;
    char* mail = (char*)d_ws;
    float* c_out = (float*)((char*)d_ws + (size_t)ncopies * 16384);

    hipMemsetAsync(mail, 0, (size_t)ncopies * 16384, stream);  // zero tags (s starts at 1)
    lstm_persistent<<<256, 256, 0, stream>>>(website, payload, W_ih, W_hh, b_ih, b_hh, mail,
                                             c_out, ncopies);
    head_kernel<<<1, 64, 0, stream>>>(c_out, W_lin, b_lin, W_out, b_out, (float*)d_out);
}